// Round 10
// baseline (128.348 us; speedup 1.0000x reference)
//
#include <hip/hip_runtime.h>
#include <cstdint>

#define Bq 16
#define Nq 512
#define Dq 12
#define HID 32
#define HEADS 4
#define Cq 8

// ws layout (float offsets)
#define OFF_G     0u         // [b][n][32]       262144
#define OFF_AS    262144u    // [b][n][4]         32768
#define OFF_AD    294912u    // [b][n][4]         32768
#define OFF_TIT   327680u    // [b][h][n]        262144  (ti, h-major)
#define OFF_TJBT  589824u    // [b][n][h]        262144  (tj+b1, n-major)
#define OFF_PACK  851968u    // u32 maskT [b][j][16]  (bit i>>4 of word i&15 = adj[i][j])

// ---- k0: per-node h, g, a_s, a_d. 8 nodes/block. (verbatim round-4) ----
__global__ __launch_bounds__(256) void k0_node(
    const float* __restrict__ x, const float* __restrict__ Wp, const float* __restrict__ bp,
    const float* __restrict__ Wg, const float* __restrict__ att_src,
    const float* __restrict__ att_dst, float* __restrict__ ws) {
    __shared__ float xs[8 * Dq];
    __shared__ float hs[8][HID];
    int n_sub = threadIdx.x >> 5;
    int k = threadIdx.x & 31;
    int node0 = blockIdx.x * 8;
    if (threadIdx.x < 8 * Dq) xs[threadIdx.x] = x[(size_t)node0 * Dq + threadIdx.x];
    __syncthreads();
    float s = bp[k];
#pragma unroll
    for (int d = 0; d < Dq; d++) s = fmaf(Wp[k * Dq + d], xs[n_sub * Dq + d], s);
    hs[n_sub][k] = s > 0.f ? s : 0.f;
    __syncthreads();
    float g = 0.f;
#pragma unroll
    for (int d = 0; d < HID; d++) g = fmaf(Wg[k * HID + d], hs[n_sub][d], g);
    int nid = node0 + n_sub;
    ws[OFF_G + (size_t)nid * HID + k] = g;
    float ss = g * att_src[k];   // k = h*8+c
    float sd = g * att_dst[k];
#pragma unroll
    for (int off = 1; off < 8; off <<= 1) {
        ss += __shfl_xor(ss, off);
        sd += __shfl_xor(sd, off);
    }
    if ((k & 7) == 0) {
        int h = k >> 3;
        ws[OFF_AS + (size_t)nid * HEADS + h] = ss;
        ws[OFF_AD + (size_t)nid * HEADS + h] = sd;
    }
}

// ---- k1_fused: 512 threads, 32-j tiles -> 256 blocks (1/CU, 2 waves/SIMD same as R4).
// Per-thread hot loop IDENTICAL to round-4; total G staging + W1 staging HALVED,
// adj loads coalesce to 128B segments. Epilogue reworked for 8-wave reduce. ----
__global__ __launch_bounds__(512, 2) void k1_fused(
    const int* __restrict__ adj, const float* __restrict__ bias_g,
    const float* __restrict__ W1, const float* __restrict__ b1,
    float* __restrict__ ws) {
    int b = blockIdx.y;
    int j0 = blockIdx.x * 32;
    int t = threadIdx.x;
    int jl = t & 31;
    int ig = t >> 5;          // 0..15
    int j = j0 + jl;

    __shared__ float smem[14752];
    // main: gs0 @0 (2304), gs1 @2304 (2304), as0 @4608 (256), as1 @4864 (256)
    // epilogue union: red @0 (36*32*9=10368), hgs @10368 (1152), W1s @11520 (2176), tjs @13696 (32*33=1056)
    float* red = smem;
    float* hgs = smem + 10368;
    float* W1s = smem + 11520;
    float* tjs = smem + 13696;

    float4 adv = *(const float4*)(ws + OFF_AD + ((size_t)b * Nq + j) * HEADS);

    const float* Gb = ws + OFF_G + (size_t)b * Nq * HID;
    const float* Ab = ws + OFF_AS + (size_t)b * Nq * HEADS;
    int ii_s = t >> 3, q_s = t & 7;   // staging: row ii_s (0..63), float4 slot q_s

    float4 ga;
    float av = 0.f;
    {   // chunk 0: load + write LDS before first barrier
        ga = *(const float4*)(Gb + (size_t)ii_s * HID + q_s * 4);
        if (t < 256) av = Ab[t];
        *(float4*)&smem[ii_s * 36 + q_s * 4] = ga;
        if (t < 256) smem[4608 + t] = av;
    }
    const int* adjp = adj + ((size_t)b * Nq + ig) * Nq + j;
    int cur[4], nxt[4];
#pragma unroll
    for (int kk = 0; kk < 4; kk++) cur[kk] = adjp[(size_t)(16 * kk) * Nq];

    float lsum[HEADS] = {0.f, 0.f, 0.f, 0.f};
    float acc[HEADS][Cq] = {};
    uint32_t mask = 0;

    for (int c = 0; c < 8; c++) {
        __syncthreads();                    // buf c&1 ready; buf (c+1)&1 free
        const float* gsc = (c & 1) ? smem + 2304 : smem;
        const float* asc = (c & 1) ? smem + 4864 : smem + 4608;
        if (c < 7) {                        // T14: issue next-chunk loads EARLY
            ga = *(const float4*)(Gb + (size_t)((c + 1) * 64 + ii_s) * HID + q_s * 4);
            if (t < 256) av = Ab[(c + 1) * 256 + t];
#pragma unroll
            for (int kk = 0; kk < 4; kk++)
                nxt[kk] = adjp[(size_t)(64 * (c + 1) + 16 * kk) * Nq];
        }
#pragma unroll
        for (int kk = 0; kk < 4; kk++) {
            int m = 4 * c + kk;              // i = 16m + ig
            int i = 16 * m + ig;
            int a = cur[kk];
            bool msk = (a != 0) || (i == j);
            mask |= (uint32_t)(a != 0) << m;
            int ii = 16 * kk + ig;
            float4 asv = *(const float4*)&asc[ii * 4];
            const float* gr = &gsc[ii * 36];
            float zs[HEADS] = {asv.x + adv.x, asv.y + adv.y, asv.z + adv.z, asv.w + adv.w};
#pragma unroll
            for (int h = 0; h < HEADS; h++) {
                float z = zs[h];
                float lk = z > 0.f ? z : 0.2f * z;
                float e = msk ? __expf(lk) : 0.f;   // no max-shift: |z| small
                lsum[h] += e;
                float4 g0 = *(const float4*)(gr + h * 8);
                float4 g1 = *(const float4*)(gr + h * 8 + 4);
                acc[h][0] = fmaf(e, g0.x, acc[h][0]);
                acc[h][1] = fmaf(e, g0.y, acc[h][1]);
                acc[h][2] = fmaf(e, g0.z, acc[h][2]);
                acc[h][3] = fmaf(e, g0.w, acc[h][3]);
                acc[h][4] = fmaf(e, g1.x, acc[h][4]);
                acc[h][5] = fmaf(e, g1.y, acc[h][5]);
                acc[h][6] = fmaf(e, g1.z, acc[h][6]);
                acc[h][7] = fmaf(e, g1.w, acc[h][7]);
            }
        }
        if (c < 7) {                        // T14: ds_write LATE (after compute)
            float* gsn = (c & 1) ? smem : smem + 2304;
            float* asn = (c & 1) ? smem + 4608 : smem + 4864;
            *(float4*)&gsn[ii_s * 36 + q_s * 4] = ga;
            if (t < 256) asn[t] = av;
#pragma unroll
            for (int kk = 0; kk < 4; kk++) cur[kk] = nxt[kk];
        }
    }

    // transposed adjacency mask for k3: word ig, bit m (each thread owns a full word)
    ((uint32_t*)(ws + OFF_PACK))[((size_t)b * Nq + j) * 16 + ig] = mask;

    __syncthreads();   // main-loop LDS dead; epilogue union usable

    {   // stage W1 (row pad 64 -> 68): 512 threads, one float4 each
        int h = t >> 4, q = t & 15;
        *(float4*)&W1s[h * 68 + q * 4] = ((const float4*)W1)[t];
    }
    // reduce over ig: xor32 pairs the wave's two igs; 8 wave-partials to LDS
    int w = t >> 6;   // 0..7
    auto dump = [&](int r, float v) {
        v += __shfl_xor(v, 32);
        if ((t & 63) < 32) red[(r * 32 + jl) * 9 + w] = v;
    };
#pragma unroll
    for (int h = 0; h < HEADS; h++) dump(h, lsum[h]);
#pragma unroll
    for (int h = 0; h < HEADS; h++)
#pragma unroll
        for (int cc = 0; cc < Cq; cc++) dump(4 + h * 8 + cc, acc[h][cc]);
    __syncthreads();
    for (int o = t; o < 1152; o += 512) {  // 36 r × 32 j totals over 8 waves
        float* pp = &red[o * 9];
        pp[8] = ((pp[0] + pp[1]) + (pp[2] + pp[3])) + ((pp[4] + pp[5]) + (pp[6] + pp[7]));
    }
    __syncthreads();
    for (int o = t; o < 1024; o += 512) {  // hg = acc/lsum + bias_g : 32 d × 32 j
        int d = o >> 5, jj = o & 31;
        float s = red[((4 + d) * 32 + jj) * 9 + 8];
        float l = red[((d >> 3) * 32 + jj) * 9 + 8];
        hgs[jj * 36 + d] = s * __builtin_amdgcn_rcpf(l) + bias_g[d];
    }
    __syncthreads();
    {   // W1 epilogue: thread (jl, tg = t>>5) computes h = tg and tg+16 for its j
        int tg = t >> 5;   // 0..15
        float si0 = 0.f, sj0 = 0.f, si1 = 0.f, sj1 = 0.f;
        const float* w0 = &W1s[tg * 68];
        const float* w1 = &W1s[(tg + 16) * 68];
        const float* hr = &hgs[jl * 36];
#pragma unroll
        for (int d = 0; d < HID; d++) {
            float hv = hr[d];
            si0 = fmaf(hv, w0[d], si0);
            sj0 = fmaf(hv, w0[32 + d], sj0);
            si1 = fmaf(hv, w1[d], si1);
            sj1 = fmaf(hv, w1[32 + d], sj1);
        }
        ws[OFF_TIT + ((size_t)b * HID + tg) * Nq + j] = si0;        // 128B segments
        ws[OFF_TIT + ((size_t)b * HID + tg + 16) * Nq + j] = si1;
        tjs[tg * 33 + jl] = sj0 + b1[tg];            // pad 33: conflict-free transpose
        tjs[(tg + 16) * 33 + jl] = sj1 + b1[tg + 16];
    }
    __syncthreads();
    for (int o = t; o < 1024; o += 512) {   // coalesced transposed store [b][n][h]
        int jj = o >> 5, h = o & 31;
        ws[OFF_TJBT + ((size_t)b * Nq + j0 + jj) * HID + h] = tjs[h * 33 + jj];
    }
}

// ---- k3: pairwise score (verbatim round-9: 8-i tiles, SGPR w2/b2, dual acc). ----
__global__ __launch_bounds__(256, 4) void k3_score(const float* __restrict__ w2_p,
                                                   const float* __restrict__ b2_p,
                                                   const float* __restrict__ ws,
                                                   float* __restrict__ out) {
    int b = blockIdx.y;
    int i0 = blockIdx.x * 8;
    int j = threadIdx.x;        // jA = j, jB = j + 256
    __shared__ float tisT[8 * 36];   // [ii][h], row pad 36
    {
        int h = threadIdx.x >> 3, ii = threadIdx.x & 7;
        tisT[ii * 36 + h] = ws[OFF_TIT + ((size_t)b * HID + h) * Nq + i0 + ii];
    }
    float4 ta[8], tb[8];
    const float* rA = ws + OFF_TJBT + ((size_t)b * Nq + j) * HID;
    const float* rB = rA + (size_t)256 * HID;
#pragma unroll
    for (int q = 0; q < 8; q++) {
        ta[q] = *(const float4*)(rA + q * 4);
        tb[q] = *(const float4*)(rB + q * 4);
    }
    float w2l[HID];
#pragma unroll
    for (int h = 0; h < HID; h++)
        w2l[h] = __int_as_float(__builtin_amdgcn_readfirstlane(__float_as_int(w2_p[h])));
    float b2 = __int_as_float(__builtin_amdgcn_readfirstlane(__float_as_int(b2_p[0])));
    const uint32_t* mrow = (const uint32_t*)(ws + OFF_PACK)
                         + ((size_t)b * Nq + j) * 16 + (i0 & 8);
    uint4 mAv[2], mBv[2];
#pragma unroll
    for (int q = 0; q < 2; q++) {
        mAv[q] = ((const uint4*)mrow)[q];
        mBv[q] = ((const uint4*)(mrow + 256 * 16))[q];
    }
    int bit = i0 >> 4;   // constant: ii<8 never crosses the 16-boundary
    __syncthreads();
#pragma unroll
    for (int ii = 0; ii < 8; ii++) {   // full unroll: all indices static
        int i = i0 + ii;
        uint32_t mA = (ii & 3) == 0 ? mAv[ii >> 2].x : (ii & 3) == 1 ? mAv[ii >> 2].y
                    : (ii & 3) == 2 ? mAv[ii >> 2].z : mAv[ii >> 2].w;
        uint32_t mB = (ii & 3) == 0 ? mBv[ii >> 2].x : (ii & 3) == 1 ? mBv[ii >> 2].y
                    : (ii & 3) == 2 ? mBv[ii >> 2].z : mBv[ii >> 2].w;
        bool onA = (((mA >> bit) & 1u) != 0) && (i != j);
        bool onB = (((mB >> bit) & 1u) != 0) && (i != j + 256);
        float sAx = b2, sAy = 0.f, sBx = b2, sBy = 0.f;
#pragma unroll
        for (int q = 0; q < 8; q++) {
            float4 tq = *(const float4*)&tisT[ii * 36 + q * 4];  // broadcast b128
            float uA0 = fmaxf(tq.x + ta[q].x, 0.f);
            float uA1 = fmaxf(tq.y + ta[q].y, 0.f);
            float uA2 = fmaxf(tq.z + ta[q].z, 0.f);
            float uA3 = fmaxf(tq.w + ta[q].w, 0.f);
            sAx = fmaf(uA0, w2l[q * 4 + 0], sAx);
            sAy = fmaf(uA1, w2l[q * 4 + 1], sAy);
            sAx = fmaf(uA2, w2l[q * 4 + 2], sAx);
            sAy = fmaf(uA3, w2l[q * 4 + 3], sAy);
            float uB0 = fmaxf(tq.x + tb[q].x, 0.f);
            float uB1 = fmaxf(tq.y + tb[q].y, 0.f);
            float uB2 = fmaxf(tq.z + tb[q].z, 0.f);
            float uB3 = fmaxf(tq.w + tb[q].w, 0.f);
            sBx = fmaf(uB0, w2l[q * 4 + 0], sBx);
            sBy = fmaf(uB1, w2l[q * 4 + 1], sBy);
            sBx = fmaf(uB2, w2l[q * 4 + 2], sBx);
            sBy = fmaf(uB3, w2l[q * 4 + 3], sBy);
        }
        float sA = sAx + sAy;
        float sB = sBx + sBy;
        float scA = __builtin_amdgcn_rcpf(1.f + __expf(-sA));
        float scB = __builtin_amdgcn_rcpf(1.f + __expf(-sB));
        out[((size_t)b * Nq + i) * Nq + j] = onA ? scA : 0.f;
        out[((size_t)b * Nq + i) * Nq + j + 256] = onB ? scB : 0.f;
    }
}

extern "C" void kernel_launch(void* const* d_in, const int* in_sizes, int n_in,
                              void* d_out, int out_size, void* d_ws, size_t ws_size,
                              hipStream_t stream) {
    const float* x       = (const float*)d_in[0];
    const int*   adj     = (const int*)d_in[1];
    const float* Wp      = (const float*)d_in[2];
    const float* bp      = (const float*)d_in[3];
    const float* Wg      = (const float*)d_in[4];
    const float* att_src = (const float*)d_in[5];
    const float* att_dst = (const float*)d_in[6];
    const float* bias_g  = (const float*)d_in[7];
    const float* W1      = (const float*)d_in[8];
    const float* b1      = (const float*)d_in[9];
    const float* w2      = (const float*)d_in[10];
    const float* b2      = (const float*)d_in[11];
    float* out = (float*)d_out;
    float* ws = (float*)d_ws;
    (void)in_sizes; (void)n_in; (void)out_size; (void)ws_size;

    k0_node<<<dim3(1024), dim3(256), 0, stream>>>(x, Wp, bp, Wg, att_src, att_dst, ws);
    k1_fused<<<dim3(Nq / 32, Bq), dim3(512), 0, stream>>>(adj, bias_g, W1, b1, ws);
    k3_score<<<dim3(64, Bq), dim3(256), 0, stream>>>(w2, b2, ws, out);
}